// Round 5
// baseline (346.302 us; speedup 1.0000x reference)
//
#include <hip/hip_runtime.h>
#include <math.h>

#define NTOK 16384
#define HDIM 2048
#define NEXP 64
#define KK   32
#define TAU  5e-5f
#define MAXB 2048    // bucket capacity per expert (mean 256, 112 sigma margin)
#define TB   32      // tokens per fused block
#define TPAD 36      // lg row stride (tokens + pad)

typedef __attribute__((ext_vector_type(8))) short short8;
typedef __attribute__((ext_vector_type(4))) float f32x4;
typedef __attribute__((ext_vector_type(4))) unsigned int uint4v;

// ws layout (4-byte units):
// [0..64)              inv_nc (f32)
// [64..128)            counts/cursor (i32)
// [128..192)           nflag + pad (i32)
// [192..16576)         route  (i32)
// [16576..32960)       flags  (i32)
// [32960..164032)      sums   (f32, 64x2048)  (fallback path only)
// [164032..295104)     bn     (f32, 64x2048)
// [295104..360640)     cbh    (u16, 64x2048 = 65536 units)  bf16-hi of c
// [360640..426176)     cbl    (u16, 64x2048 = 65536 units)  bf16-lo of c
// [426176..557248)     bucket (i32, 64x2048)
// [557248..1081536)    psum   (f32, 4x64x2048)   total ~4.33 MB

__global__ __launch_bounds__(256)
void zero_kernel(float* p, int n) {
  int i = blockIdx.x * 256 + threadIdx.x;
  if (i < n) p[i] = 0.0f;
}

__device__ __forceinline__ float block_reduce_sum(float v, float* red) {
  #pragma unroll
  for (int o = 32; o > 0; o >>= 1) v += __shfl_down(v, o, 64);
  int lane = threadIdx.x & 63;
  int wid  = threadIdx.x >> 6;
  if (lane == 0) red[wid] = v;
  __syncthreads();
  float s = red[0] + red[1] + red[2] + red[3];
  __syncthreads();
  return s;
}

__device__ __forceinline__ double block_reduce_sum_f64(double v, double* red) {
  const int tid = threadIdx.x;
  red[tid] = v;
  __syncthreads();
  if (tid < 128) red[tid] += red[tid + 128];
  __syncthreads();
  if (tid < 64)  red[tid] += red[tid + 64];
  __syncthreads();
  double s = 0.0;
  if (tid < 64) {
    s = red[tid];
    #pragma unroll
    for (int o = 32; o > 0; o >>= 1) s += __shfl_down(s, o, 64);
  }
  if (tid == 0) red[0] = s;
  __syncthreads();
  s = red[0];
  __syncthreads();
  return s;
}

__global__ __launch_bounds__(256)
void cnorm_kernel(const float* __restrict__ c, float* __restrict__ inv_nc) {
  __shared__ float red[4];
  int e = blockIdx.x;
  float ss = 0.f;
  #pragma unroll
  for (int j = 0; j < 8; ++j) {
    float v = c[e * HDIM + threadIdx.x + j * 256];
    ss += v * v;
  }
  float tot = block_reduce_sum(ss, red);
  if (threadIdx.x == 0) inv_nc[e] = 1.0f / fmaxf(sqrtf(tot), 1e-12f);
}

// Center prep: fp32 inv-norm, fp64 bn, bf16 hi/lo split of c, and zero cursor/nflag.
__global__ __launch_bounds__(256)
void cprep_kernel(const float* __restrict__ c, float* __restrict__ inv_nc,
                  float* __restrict__ bn, unsigned short* __restrict__ cbh,
                  unsigned short* __restrict__ cbl, int* __restrict__ zr) {
  __shared__ float red[4];
  __shared__ double redd[256];
  __shared__ float s_nc;
  const int e = blockIdx.x;
  const int tid = threadIdx.x;
  if (e == 0 && tid < 128) zr[tid] = 0;   // cursor[64] + nflag block
  const float* cr = c + (size_t)e * HDIM;
  float ss = 0.f;
  double acc = 0.0;
  #pragma unroll
  for (int j = 0; j < 8; ++j) {
    float v = cr[tid + j * 256];
    ss += v * v;
    double dv = (double)v;
    acc += dv * dv;
  }
  float tot = block_reduce_sum(ss, red);
  double cn = block_reduce_sum_f64(acc, redd);
  if (tid == 0) {
    inv_nc[e] = 1.0f / fmaxf(sqrtf(tot), 1e-12f);
    s_nc = (float)fmax(sqrt(cn), 1e-12);
  }
  __syncthreads();
  const double nc = (double)s_nc;
  #pragma unroll
  for (int j = 0; j < 8; ++j) {
    const int k = tid + j * 256;
    const float v = cr[k];
    bn[(size_t)e * HDIM + k] = (float)((double)v / nc);
    unsigned u = __float_as_uint(v);
    unsigned h = u & 0xffff0000u;
    float r = v - __uint_as_float(h);
    cbh[(size_t)e * HDIM + k] = (unsigned short)(u >> 16);
    cbl[(size_t)e * HDIM + k] = (unsigned short)(__float_as_uint(r) >> 16);
  }
}

// split fp32 pair into bf16 hi (truncation) + bf16 lo (truncated residual), packed 2-wide.
__device__ __forceinline__ void cvt2(float v0, float v1, unsigned &hi, unsigned &lo) {
  unsigned u0 = __float_as_uint(v0);
  unsigned u1 = __float_as_uint(v1);
  unsigned h0 = u0 & 0xffff0000u;
  unsigned h1 = u1 & 0xffff0000u;
  float r0 = v0 - __uint_as_float(h0);
  float r1 = v1 - __uint_as_float(h1);
  hi = (u0 >> 16) | h1;
  lo = (__float_as_uint(r0) >> 16) | (__float_as_uint(r1) & 0xffff0000u);
}

// Fused full-K router v2: 32 tokens x 64 experts x K=2048 per block.
// Barrier-free K-loop: per-lane direct global loads of A/B fragments,
// 4-slot register pipeline (~3 iterations in flight). One barrier before epilogue.
// wave w: token tile (w&1)*16, expert half (w>>1)*32. Waves 0/2 and 1/3
// duplicate x reads (L1/L2 absorb; HBM traffic unchanged).
__global__ __launch_bounds__(256)
void fused_kernel(const float* __restrict__ x,
                  const unsigned short* __restrict__ cbh,
                  const unsigned short* __restrict__ cbl,
                  const float* __restrict__ inv_nc,
                  float* __restrict__ out, int* __restrict__ route,
                  int* __restrict__ nflag, int* __restrict__ flags) {
  __shared__ float lg[NEXP][TPAD];   // 9 KB
  __shared__ float xn_lds[TB];
  __shared__ float snc[NEXP];

  const int tid  = threadIdx.x;
  const int t0   = blockIdx.x * TB;
  const int lane = tid & 63;
  const int w    = tid >> 6;
  const int tt   = (w & 1) * 16;      // wave's token tile
  const int eh   = (w >> 1) * 32;     // wave's expert half
  const int fr   = lane & 15;
  const int fk   = (lane >> 4) * 8;   // 8 consecutive k per lane

  if (tid < NEXP) snc[tid] = inv_nc[tid];

  const float*          xa  = x   + (size_t)(t0 + tt + fr) * HDIM + fk;
  const unsigned short* b0h = cbh + (size_t)(eh + fr)      * HDIM + fk;
  const unsigned short* b0l = cbl + (size_t)(eh + fr)      * HDIM + fk;
  const unsigned short* b1h = cbh + (size_t)(eh + 16 + fr) * HDIM + fk;
  const unsigned short* b1l = cbl + (size_t)(eh + 16 + fr) * HDIM + fk;

  f32x4 acc0 = (f32x4){0.f, 0.f, 0.f, 0.f};
  f32x4 acc1 = (f32x4){0.f, 0.f, 0.f, 0.f};
  float nacc = 0.f;

  union U { uint4v u; short8 s; };

  f32x4  Aa0, Aa1, Ba0, Ba1, Ca0, Ca1, Da0, Da1;
  short8 Ah0, Al0, Ah1, Al1;
  short8 Bh0, Bl0, Bh1, Bl1;
  short8 Ch0, Cl0, Ch1, Cl1;
  short8 Dh0, Dl0, Dh1, Dl1;

  #define LDSLOT(S, i) do { const int o_ = (i) * KK;                      \
    S##a0 = *(const f32x4*)(xa + o_);                                     \
    S##a1 = *(const f32x4*)(xa + o_ + 4);                                 \
    S##h0 = *(const short8*)(b0h + o_);                                   \
    S##l0 = *(const short8*)(b0l + o_);                                   \
    S##h1 = *(const short8*)(b1h + o_);                                   \
    S##l1 = *(const short8*)(b1l + o_); } while (0)

  #define CONSUME(S) do {                                                 \
    unsigned h01_, l01_, h23_, l23_, h45_, l45_, h67_, l67_;              \
    cvt2(S##a0.x, S##a0.y, h01_, l01_);                                   \
    cvt2(S##a0.z, S##a0.w, h23_, l23_);                                   \
    cvt2(S##a1.x, S##a1.y, h45_, l45_);                                   \
    cvt2(S##a1.z, S##a1.w, h67_, l67_);                                   \
    U ah_; ah_.u = (uint4v){h01_, h23_, h45_, h67_};                      \
    U al_; al_.u = (uint4v){l01_, l23_, l45_, l67_};                      \
    nacc += S##a0.x*S##a0.x + S##a0.y*S##a0.y + S##a0.z*S##a0.z + S##a0.w*S##a0.w \
          + S##a1.x*S##a1.x + S##a1.y*S##a1.y + S##a1.z*S##a1.z + S##a1.w*S##a1.w; \
    acc0 = __builtin_amdgcn_mfma_f32_16x16x32_bf16(ah_.s, S##h0, acc0, 0, 0, 0); \
    acc0 = __builtin_amdgcn_mfma_f32_16x16x32_bf16(ah_.s, S##l0, acc0, 0, 0, 0); \
    acc0 = __builtin_amdgcn_mfma_f32_16x16x32_bf16(al_.s, S##h0, acc0, 0, 0, 0); \
    acc1 = __builtin_amdgcn_mfma_f32_16x16x32_bf16(ah_.s, S##h1, acc1, 0, 0, 0); \
    acc1 = __builtin_amdgcn_mfma_f32_16x16x32_bf16(ah_.s, S##l1, acc1, 0, 0, 0); \
    acc1 = __builtin_amdgcn_mfma_f32_16x16x32_bf16(al_.s, S##h1, acc1, 0, 0, 0); \
  } while (0)

  LDSLOT(A, 0);
  LDSLOT(B, 1);
  LDSLOT(C, 2);

  #pragma unroll 1
  for (int it = 0; it < 64; it += 4) {
    LDSLOT(D, it + 3);
    CONSUME(A);
    if (it + 4 < 64) LDSLOT(A, it + 4);
    CONSUME(B);
    if (it + 5 < 64) LDSLOT(B, it + 5);
    CONSUME(C);
    if (it + 6 < 64) LDSLOT(C, it + 6);
    CONSUME(D);
  }
  #undef LDSLOT
  #undef CONSUME

  // token norms: lanes fr, fr+16, fr+32, fr+48 hold the 4 k-group partials
  float s = nacc;
  s += __shfl_xor(s, 16, 64);
  s += __shfl_xor(s, 32, 64);
  if (lane < 16) xn_lds[tt + lane] = s;   // waves 0/2 (and 1/3) dup-write same value

  // logits -> LDS [e][t]; D frag: col(expert)=lane&15, row(token)=(lane>>4)*4+reg
  const int tb = tt + (lane >> 4) * 4;
  *(f32x4*)&lg[eh + fr][tb]      = acc0;
  *(f32x4*)&lg[eh + 16 + fr][tb] = acc1;
  __syncthreads();

  if (tid < TB) {
    const int t  = tid;
    const int tg = t0 + t;
    const float inv_nx = 1.0f / fmaxf(sqrtf(xn_lds[t]), 1e-12f);
    float m1 = -1e30f, m2 = -1e30f, m3 = -1e30f;
    int i1 = 0, i2 = 0;
    #pragma unroll
    for (int e = 0; e < NEXP; ++e) {
      float l = lg[e][t] * snc[e] * inv_nx;
      if (l > m1)      { m3 = m2; m2 = m1; i2 = i1; m1 = l; i1 = e; }
      else if (l > m2) { m3 = m2; m2 = l; i2 = e; }
      else if (l > m3) { m3 = l; }
    }
    float Z = 0.f;
    #pragma unroll
    for (int e = 0; e < NEXP; ++e)
      Z += expf(lg[e][t] * snc[e] * inv_nx - m1);
    const float p1w = 1.0f / Z;
    const float p2w = expf(m2 - m1) / Z;
    const float s2  = p1w + p2w + 1e-9f;
    out[tg * 2 + 0] = (float)i1;
    out[tg * 2 + 1] = (float)i2;
    out[2 * NTOK + tg * 2 + 0] = p1w / s2;
    out[2 * NTOK + tg * 2 + 1] = p2w / s2;
    route[tg] = i1;
    if ((m1 - m2) < TAU || (m2 - m3) < TAU) {
      int idx = atomicAdd(nflag, 1);
      flags[idx] = tg;
    }
  }
}

// Refine v2 (R8, known-good): block per flagged token.
__global__ __launch_bounds__(256)
void refine_np_kernel(const float* __restrict__ x, const float* __restrict__ bn,
                      float* __restrict__ out, int* __restrict__ route,
                      const int* __restrict__ nflag, const int* __restrict__ flags) {
  __shared__ float a_lds[HDIM];
  __shared__ double redd[256];
  __shared__ float lf[NEXP];
  __shared__ float s_nx;
  const int tid  = threadIdx.x;
  const int lane = tid & 63;
  const int w    = tid >> 6;
  const int n = *nflag;
  for (int j = blockIdx.x; j < n; j += gridDim.x) {
    const int t = flags[j];
    const float* xr = x + (size_t)t * HDIM;
    double xacc = 0.0;
    #pragma unroll
    for (int i = 0; i < 8; ++i) {
      double v = (double)xr[tid + 256 * i];
      xacc += v * v;
    }
    double xn = block_reduce_sum_f64(xacc, redd);
    if (tid == 0) s_nx = (float)fmax(sqrt(xn), 1e-12);
    __syncthreads();
    const double nx = (double)s_nx;
    #pragma unroll
    for (int i = 0; i < 8; ++i) {
      int k = tid + 256 * i;
      a_lds[k] = (float)((double)xr[k] / nx);
    }
    __syncthreads();
    #pragma unroll 1
    for (int ei = 0; ei < 16; ++ei) {
      const int e = w * 16 + ei;
      const float* br = bn + (size_t)e * HDIM;
      double d = 0.0;
      #pragma unroll 8
      for (int i = 0; i < 32; ++i) {
        int k = lane + 64 * i;
        d += (double)a_lds[k] * (double)br[k];
      }
      #pragma unroll
      for (int o = 32; o > 0; o >>= 1) d += __shfl_down(d, o, 64);
      if (lane == 0) lf[e] = (float)d;
    }
    __syncthreads();
    if (tid == 0) {
      float m32 = lf[0];
      for (int ee = 1; ee < NEXP; ++ee) m32 = fmaxf(m32, lf[ee]);
      float ex[NEXP];
      for (int ee = 0; ee < NEXP; ++ee)
        ex[ee] = (float)exp((double)(lf[ee] - m32));
      float r[8];
      #pragma unroll
      for (int q = 0; q < 8; ++q) r[q] = ex[q];
      for (int i = 8; i < NEXP; i += 8)
        #pragma unroll
        for (int q = 0; q < 8; ++q) r[q] += ex[i + q];
      const float Z = ((r[0] + r[1]) + (r[2] + r[3])) + ((r[4] + r[5]) + (r[6] + r[7]));
      float p1 = -1.f, p2 = -1.f;
      int i1 = 0, i2 = 0;
      for (int ee = 0; ee < NEXP; ++ee) {
        float p = ex[ee] / Z;
        if (p > p1)      { p2 = p1; i2 = i1; p1 = p; i1 = ee; }
        else if (p > p2) { p2 = p; i2 = ee; }
      }
      const float s = (p1 + p2) + 1e-9f;
      out[t * 2 + 0] = (float)i1;
      out[t * 2 + 1] = (float)i2;
      out[2 * NTOK + t * 2 + 0] = p1 / s;
      out[2 * NTOK + t * 2 + 1] = p2 / s;
      route[t] = i1;
    }
    __syncthreads();
  }
}

// slow fallback refine (no bn dependency) for small-ws path
__global__ __launch_bounds__(64)
void refine_np_slow(const float* __restrict__ x, const float* __restrict__ c,
                    float* __restrict__ out, int* __restrict__ route,
                    const int* __restrict__ nflag, const int* __restrict__ flags) {
  __shared__ float lf[NEXP];
  const int e = threadIdx.x;
  const int n = *nflag;
  for (int j = blockIdx.x; j < n; j += gridDim.x) {
    const int t = flags[j];
    const float* xr = x + (size_t)t * HDIM;
    const float* cr = c + (size_t)e * HDIM;
    double xn = 0.0, cn = 0.0;
    for (int k = 0; k < HDIM; ++k) {
      double xv = (double)xr[k];
      double cv = (double)cr[k];
      xn += xv * xv;
      cn += cv * cv;
    }
    const float nx32 = (float)fmax(sqrt(xn), 1e-12);
    const float nc32 = (float)fmax(sqrt(cn), 1e-12);
    double d = 0.0;
    for (int k = 0; k < HDIM; ++k) {
      float a = (float)((double)xr[k] / (double)nx32);
      float b = (float)((double)cr[k] / (double)nc32);
      d += (double)a * (double)b;
    }
    lf[e] = (float)d;
    __syncthreads();
    if (e == 0) {
      float m32 = lf[0];
      for (int ee = 1; ee < NEXP; ++ee) m32 = fmaxf(m32, lf[ee]);
      float ex[NEXP];
      for (int ee = 0; ee < NEXP; ++ee)
        ex[ee] = (float)exp((double)(lf[ee] - m32));
      float r[8];
      #pragma unroll
      for (int q = 0; q < 8; ++q) r[q] = ex[q];
      for (int i = 8; i < NEXP; i += 8)
        #pragma unroll
        for (int q = 0; q < 8; ++q) r[q] += ex[i + q];
      const float Z = ((r[0] + r[1]) + (r[2] + r[3])) + ((r[4] + r[5]) + (r[6] + r[7]));
      float p1 = -1.f, p2 = -1.f;
      int i1 = 0, i2 = 0;
      for (int ee = 0; ee < NEXP; ++ee) {
        float p = ex[ee] / Z;
        if (p > p1)      { p2 = p1; i2 = i1; p1 = p; i1 = ee; }
        else if (p > p2) { p2 = p; i2 = ee; }
      }
      const float s = (p1 + p2) + 1e-9f;
      out[t * 2 + 0] = (float)i1;
      out[t * 2 + 1] = (float)i2;
      out[2 * NTOK + t * 2 + 0] = p1 / s;
      out[2 * NTOK + t * 2 + 1] = p2 / s;
      route[t] = i1;
    }
    __syncthreads();
  }
}

// Bucket scatter: cursor[e] counts tokens (== counts), bucket[e][pos] = t.
// Must run AFTER refine (refine can flip route).
__global__ __launch_bounds__(256)
void scatter_kernel(const int* __restrict__ route, int* __restrict__ cursor,
                    int* __restrict__ bucket) {
  const int t = blockIdx.x * 256 + threadIdx.x;
  const int e = route[t];
  const int pos = atomicAdd(&cursor[e], 1);
  if (pos < MAXB) bucket[e * MAXB + pos] = t;
}

// Per-expert partial sums, 4-way token split: block = (expert, hchunk, tsplit).
// grid = 64*8*4 = 2048 blocks (8/CU). float4 per thread, 4 rows in flight.
__global__ __launch_bounds__(256)
void segsum_part(const float* __restrict__ x, const int* __restrict__ cursor,
                 const int* __restrict__ bucket, float* __restrict__ psum) {
  __shared__ f32x4 part[4][64];
  const int e   = blockIdx.x >> 5;
  const int hc  = (blockIdx.x >> 2) & 7;
  const int ts  = blockIdx.x & 3;
  const int hb  = hc * 256;
  const int tid = threadIdx.x;
  const int rg  = tid >> 6;
  const int cc  = tid & 63;
  int n = cursor[e];
  if (n > MAXB) n = MAXB;
  const int nq = (n + 3) >> 2;
  const int lo = ts * nq;
  const int hi = min(lo + nq, n);
  const int* bk = bucket + e * MAXB;
  f32x4 a = (f32x4){0.f, 0.f, 0.f, 0.f};
  #pragma unroll 4
  for (int i = lo + rg; i < hi; i += 4)
    a += *(const f32x4*)(x + (size_t)bk[i] * HDIM + hb + cc * 4);
  part[rg][cc] = a;
  __syncthreads();
  if (tid < 64) {
    f32x4 s = part[0][tid] + part[1][tid] + part[2][tid] + part[3][tid];
    *(f32x4*)&psum[(size_t)(ts * NEXP + e) * HDIM + hb + tid * 4] = s;
  }
}

__global__ __launch_bounds__(256)
void finalize4_kernel(const float* __restrict__ c, const float* __restrict__ psum,
                      const int* __restrict__ counts, float* __restrict__ out) {
  __shared__ float red[4];
  const int e = blockIdx.x;
  const int tid = threadIdx.x;
  const float cnt = (float)counts[e];
  const float minv = 1.0f / (cnt + 1e-6f);
  float u[8], cv[8];
  float ss = 0.f;
  #pragma unroll
  for (int j = 0; j < 8; ++j) {
    int h = tid + j * 256;
    cv[j] = c[e * HDIM + h];
    float sm = psum[(size_t)(0 * NEXP + e) * HDIM + h]
             + psum[(size_t)(1 * NEXP + e) * HDIM + h]
             + psum[(size_t)(2 * NEXP + e) * HDIM + h]
             + psum[(size_t)(3 * NEXP + e) * HDIM + h];
    float mean = sm * minv;
    u[j] = 0.9f * cv[j] + 0.1f * mean;
    ss += u[j] * u[j];
  }
  float tot = block_reduce_sum(ss, red);
  float sc = 1.0f / fmaxf(sqrtf(tot), 1e-12f);
  const bool nz = cnt > 0.f;
  #pragma unroll
  for (int j = 0; j < 8; ++j) {
    int h = tid + j * 256;
    out[4 * NTOK + e * HDIM + h] = nz ? u[j] * sc : cv[j];
  }
}

__global__ __launch_bounds__(256)
void finalize_kernel(const float* __restrict__ c, const float* __restrict__ sums,
                     const int* __restrict__ counts, float* __restrict__ out) {
  __shared__ float red[4];
  const int e = blockIdx.x;
  const int tid = threadIdx.x;
  const float cnt = (float)counts[e];
  const float minv = 1.0f / (cnt + 1e-6f);
  float u[8], cv[8];
  float ss = 0.f;
  #pragma unroll
  for (int j = 0; j < 8; ++j) {
    int h = tid + j * 256;
    cv[j] = c[e * HDIM + h];
    float mean = sums[e * HDIM + h] * minv;
    u[j] = 0.9f * cv[j] + 0.1f * mean;
    ss += u[j] * u[j];
  }
  float tot = block_reduce_sum(ss, red);
  float sc = 1.0f / fmaxf(sqrtf(tot), 1e-12f);
  const bool nz = cnt > 0.f;
  #pragma unroll
  for (int j = 0; j < 8; ++j) {
    int h = tid + j * 256;
    out[4 * NTOK + e * HDIM + h] = nz ? u[j] * sc : cv[j];
  }
}

// ---- fallback path kernels (small ws): R5 router + old segsum ----
__global__ __launch_bounds__(256)
void router_kernel(const float* __restrict__ x, const float* __restrict__ c,
                   const float* __restrict__ inv_nc, float* __restrict__ out,
                   int* __restrict__ route, int* __restrict__ nflag,
                   int* __restrict__ flags) {
  __shared__ __align__(16) float xs[64][36];
  __shared__ float lgs[64][67];
  const int tid  = threadIdx.x;
  const int lane = tid & 63;
  const int w    = tid >> 6;
  const int t0   = blockIdx.x * 64;
  const int e0   = __builtin_amdgcn_readfirstlane(w * 16);
  const float* cb = c + (size_t)e0 * HDIM;
  const int st = tid >> 3;
  const int sk = (tid & 7) * 4;
  float acc[16];
  #pragma unroll
  for (int e = 0; e < 16; ++e) acc[e] = 0.f;
  float nacc = 0.f;
  float4 p0 = *(const float4*)&x[(size_t)(t0 + st)      * HDIM + sk];
  float4 p1 = *(const float4*)&x[(size_t)(t0 + st + 32) * HDIM + sk];
  for (int k0 = 0; k0 < HDIM; k0 += 32) {
    __syncthreads();
    *(float4*)&xs[st][sk]      = p0;
    *(float4*)&xs[st + 32][sk] = p1;
    __syncthreads();
    const int kn = k0 + 32;
    if (kn < HDIM) {
      p0 = *(const float4*)&x[(size_t)(t0 + st)      * HDIM + kn + sk];
      p1 = *(const float4*)&x[(size_t)(t0 + st + 32) * HDIM + kn + sk];
    }
    float a[32];
    #pragma unroll
    for (int j = 0; j < 32; j += 4) {
      float4 v = *(const float4*)&xs[lane][j];
      a[j] = v.x; a[j+1] = v.y; a[j+2] = v.z; a[j+3] = v.w;
    }
    if (w == 0) {
      #pragma unroll
      for (int j = 0; j < 32; ++j) nacc += a[j] * a[j];
    }
    #pragma unroll
    for (int e = 0; e < 16; ++e) {
      const float* br = cb + (size_t)e * HDIM + k0;
      #pragma unroll
      for (int j = 0; j < 32; j += 4) {
        float4 bv = *(const float4*)&br[j];
        acc[e] += a[j]*bv.x + a[j+1]*bv.y + a[j+2]*bv.z + a[j+3]*bv.w;
      }
    }
  }
  #pragma unroll
  for (int e = 0; e < 16; ++e) lgs[lane][e0 + e] = acc[e] * inv_nc[e0 + e];
  __syncthreads();
  if (w == 0) {
    const float inv_nx = 1.0f / fmaxf(sqrtf(nacc), 1e-12f);
    float m1 = -1e30f, m2 = -1e30f, m3 = -1e30f;
    int i1 = 0, i2 = 0;
    for (int e = 0; e < NEXP; ++e) {
      float l = lgs[lane][e] * inv_nx;
      if (l > m1)      { m3 = m2; m2 = m1; i2 = i1; m1 = l; i1 = e; }
      else if (l > m2) { m3 = m2; m2 = l; i2 = e; }
      else if (l > m3) { m3 = l; }
    }
    float Z = 0.f;
    for (int e = 0; e < NEXP; ++e) Z += expf(lgs[lane][e] * inv_nx - m1);
    const float p1w = 1.0f / Z;
    const float p2w = expf(m2 - m1) / Z;
    const float s   = p1w + p2w + 1e-9f;
    const int tg = t0 + lane;
    out[tg * 2 + 0] = (float)i1;
    out[tg * 2 + 1] = (float)i2;
    out[2 * NTOK + tg * 2 + 0] = p1w / s;
    out[2 * NTOK + tg * 2 + 1] = p2w / s;
    route[tg] = i1;
    if ((m1 - m2) < TAU || (m2 - m3) < TAU) {
      int idx = atomicAdd(nflag, 1);
      flags[idx] = tg;
    }
  }
}

__global__ __launch_bounds__(512)
void segsum_kernel(const float* __restrict__ x, const int* __restrict__ route,
                   float* __restrict__ sums, int* __restrict__ counts) {
  __shared__ float ls[NEXP * 256];
  __shared__ int lcnt[NEXP];
  const int tid  = threadIdx.x;
  const int lane = tid & 63;
  const int w    = tid >> 6;
  const int hc   = blockIdx.x & 7;
  const int tg   = blockIdx.x >> 3;
  const int hb   = hc * 256;
  #pragma unroll
  for (int i = 0; i < 32; ++i) ls[tid + i * 512] = 0.f;
  if (tid < NEXP) lcnt[tid] = 0;
  __syncthreads();
  const int tbase = tg * 512 + w * 64;
  #pragma unroll 4
  for (int i = 0; i < 64; ++i) {
    const int t = tbase + i;
    const int e = route[t];
    const float* xr = x + (size_t)t * HDIM + hb + lane;
    #pragma unroll
    for (int j = 0; j < 4; ++j)
      atomicAdd(&ls[e * 256 + lane + 64 * j], xr[64 * j]);
    if (hc == 0 && lane == 0) atomicAdd(&lcnt[e], 1);
  }
  __syncthreads();
  #pragma unroll
  for (int i = tid; i < NEXP * 256; i += 512) {
    const int e = i >> 8, h = i & 255;
    atomicAdd(&sums[e * HDIM + hb + h], ls[i]);
  }
  if (hc == 0 && tid < NEXP && lcnt[tid] > 0) atomicAdd(&counts[tid], lcnt[tid]);
}

extern "C" void kernel_launch(void* const* d_in, const int* in_sizes, int n_in,
                              void* d_out, int out_size, void* d_ws, size_t ws_size,
                              hipStream_t stream) {
  const float* x = (const float*)d_in[0];
  const float* c = (const float*)d_in[1];
  float* out = (float*)d_out;
  float* ws = (float*)d_ws;

  float* inv_nc = ws;
  int*   counts = (int*)(ws + 64);      // == cursor
  int*   nflag  = (int*)(ws + 128);
  int*   route  = (int*)(ws + 192);
  int*   flags  = (int*)(ws + 16576);
  float* sums   = ws + 32960;           // fallback path only
  float* bn     = ws + 164032;
  unsigned short* cbh = (unsigned short*)(ws + 295104);
  unsigned short* cbl = (unsigned short*)(ws + 360640);
  int*   bucket = (int*)(ws + 426176);
  float* psum   = ws + 557248;

  const size_t NEED = 1081536ull * 4ull;
  if (ws_size >= NEED) {
    cprep_kernel<<<NEXP, 256, 0, stream>>>(c, inv_nc, bn, cbh, cbl, counts);
    fused_kernel<<<NTOK / TB, 256, 0, stream>>>(x, cbh, cbl, inv_nc, out, route, nflag, flags);
    refine_np_kernel<<<512, 256, 0, stream>>>(x, bn, out, route, nflag, flags);
    scatter_kernel<<<64, 256, 0, stream>>>(route, counts, bucket);
    segsum_part<<<2048, 256, 0, stream>>>(x, counts, bucket, psum);
    finalize4_kernel<<<NEXP, 256, 0, stream>>>(c, psum, counts, out);
  } else {
    zero_kernel<<<1, 256, 0, stream>>>(ws + 64, 128);
    zero_kernel<<<512, 256, 0, stream>>>(sums, 131072);
    cnorm_kernel<<<NEXP, 256, 0, stream>>>(c, inv_nc);
    router_kernel<<<NTOK / 64, 256, 0, stream>>>(x, c, inv_nc, out, route, nflag, flags);
    refine_np_slow<<<1024, 64, 0, stream>>>(x, c, out, route, nflag, flags);
    segsum_kernel<<<256, 512, 0, stream>>>(x, route, sums, counts);
    finalize_kernel<<<NEXP, 256, 0, stream>>>(c, sums, counts, out);
  }
}

// Round 6
// 310.264 us; speedup vs baseline: 1.1162x; 1.1162x over previous
//
#include <hip/hip_runtime.h>
#include <math.h>

#define NTOK 16384
#define HDIM 2048
#define NEXP 64
#define KK   32
#define TAU  5e-5f
#define MAXB 2048    // bucket capacity per expert (mean 256, 112 sigma margin)
#define TB   16      // tokens per fused block
#define KPAD 40      // LDS u16 row stride: 80B = 20 banks -> only free 2-way alias
#define TPAD 20      // lg row stride (tokens + pad), 80B rows, 16B-aligned

typedef __attribute__((ext_vector_type(8))) short short8;
typedef __attribute__((ext_vector_type(4))) float f32x4;
typedef __attribute__((ext_vector_type(2))) unsigned int uint2v;

// ws layout (4-byte units):
// [0..64)              inv_nc (f32)
// [64..128)            cursor (i32, bucket fill counters)
// [128..192)           nflag + pad (i32)
// [192..16576)         route  (i32)
// [16576..32960)       flags  (i32)
// [32960..164032)      sums   (f32, 64x2048)  (fallback path only)
// [164032..295104)     bn     (f32, 64x2048)
// [295104..360640)     cbh    (u16, 64x2048 = 65536 units)  bf16-hi of c
// [360640..426176)     cbl    (u16, 64x2048 = 65536 units)  bf16-lo of c
// [426176..557248)     bucket (i32, 64x2048)
// [557248..1081536)    psum   (f32, 4x64x2048)
// [1081536..1097920)   posa   (i32, 16384)  token -> bucket slot
// [1097920..1097984)   cnt    (i32, 64)     exact per-expert counts

__global__ __launch_bounds__(256)
void zero_kernel(float* p, int n) {
  int i = blockIdx.x * 256 + threadIdx.x;
  if (i < n) p[i] = 0.0f;
}

__device__ __forceinline__ float block_reduce_sum(float v, float* red) {
  #pragma unroll
  for (int o = 32; o > 0; o >>= 1) v += __shfl_down(v, o, 64);
  int lane = threadIdx.x & 63;
  int wid  = threadIdx.x >> 6;
  if (lane == 0) red[wid] = v;
  __syncthreads();
  float s = red[0] + red[1] + red[2] + red[3];
  __syncthreads();
  return s;
}

__device__ __forceinline__ double block_reduce_sum_f64(double v, double* red) {
  const int tid = threadIdx.x;
  red[tid] = v;
  __syncthreads();
  if (tid < 128) red[tid] += red[tid + 128];
  __syncthreads();
  if (tid < 64)  red[tid] += red[tid + 64];
  __syncthreads();
  double s = 0.0;
  if (tid < 64) {
    s = red[tid];
    #pragma unroll
    for (int o = 32; o > 0; o >>= 1) s += __shfl_down(s, o, 64);
  }
  if (tid == 0) red[0] = s;
  __syncthreads();
  s = red[0];
  __syncthreads();
  return s;
}

__global__ __launch_bounds__(256)
void cnorm_kernel(const float* __restrict__ c, float* __restrict__ inv_nc) {
  __shared__ float red[4];
  int e = blockIdx.x;
  float ss = 0.f;
  #pragma unroll
  for (int j = 0; j < 8; ++j) {
    float v = c[e * HDIM + threadIdx.x + j * 256];
    ss += v * v;
  }
  float tot = block_reduce_sum(ss, red);
  if (threadIdx.x == 0) inv_nc[e] = 1.0f / fmaxf(sqrtf(tot), 1e-12f);
}

// Center prep: fp32 inv-norm, fp64 bn, bf16 hi/lo split of c, zero counters.
__global__ __launch_bounds__(256)
void cprep_kernel(const float* __restrict__ c, float* __restrict__ inv_nc,
                  float* __restrict__ bn, unsigned short* __restrict__ cbh,
                  unsigned short* __restrict__ cbl, int* __restrict__ zr,
                  int* __restrict__ cnt) {
  __shared__ float red[4];
  __shared__ double redd[256];
  __shared__ float s_nc;
  const int e = blockIdx.x;
  const int tid = threadIdx.x;
  if (e == 0 && tid < 128) zr[tid] = 0;   // cursor[64] + nflag block
  if (e == 1 && tid < 64)  cnt[tid] = 0;
  const float* cr = c + (size_t)e * HDIM;
  float ss = 0.f;
  double acc = 0.0;
  #pragma unroll
  for (int j = 0; j < 8; ++j) {
    float v = cr[tid + j * 256];
    ss += v * v;
    double dv = (double)v;
    acc += dv * dv;
  }
  float tot = block_reduce_sum(ss, red);
  double cn = block_reduce_sum_f64(acc, redd);
  if (tid == 0) {
    inv_nc[e] = 1.0f / fmaxf(sqrtf(tot), 1e-12f);
    s_nc = (float)fmax(sqrt(cn), 1e-12);
  }
  __syncthreads();
  const double nc = (double)s_nc;
  #pragma unroll
  for (int j = 0; j < 8; ++j) {
    const int k = tid + j * 256;
    const float v = cr[k];
    bn[(size_t)e * HDIM + k] = (float)((double)v / nc);
    unsigned u = __float_as_uint(v);
    unsigned h = u & 0xffff0000u;
    float r = v - __uint_as_float(h);
    cbh[(size_t)e * HDIM + k] = (unsigned short)(u >> 16);
    cbl[(size_t)e * HDIM + k] = (unsigned short)(__float_as_uint(r) >> 16);
  }
}

// split fp32 pair into bf16 hi (truncation) + bf16 lo (truncated residual), packed 2-wide.
__device__ __forceinline__ void cvt2(float v0, float v1, unsigned &hi, unsigned &lo) {
  unsigned u0 = __float_as_uint(v0);
  unsigned u1 = __float_as_uint(v1);
  unsigned h0 = u0 & 0xffff0000u;
  unsigned h1 = u1 & 0xffff0000u;
  float r0 = v0 - __uint_as_float(h0);
  float r1 = v1 - __uint_as_float(h1);
  hi = (u0 >> 16) | h1;
  lo = (__float_as_uint(r0) >> 16) | (__float_as_uint(r1) & 0xffff0000u);
}

// Fused full-K router v3: 16 tokens x 64 experts x K=2048 per 128-thread block.
// Coalesced LDS double-buffer staging (round-4 verified scheme), KPAD=40 pad
// kills bank conflicts, grid 1024 -> 4 independent blocks/CU for latency hiding.
// Epilogue: softmax/top-2 + bucket scatter (cursor/cnt/bucket/posa).
__global__ __launch_bounds__(128)
void fused_kernel(const float* __restrict__ x,
                  const unsigned short* __restrict__ cbh,
                  const unsigned short* __restrict__ cbl,
                  const float* __restrict__ inv_nc,
                  float* __restrict__ out, int* __restrict__ route,
                  int* __restrict__ nflag, int* __restrict__ flags,
                  int* __restrict__ cursor, int* __restrict__ cnt,
                  int* __restrict__ bucket, int* __restrict__ posa) {
  __shared__ __align__(16) unsigned short Ah[2][TB][KPAD];     // 2.5 KB
  __shared__ __align__(16) unsigned short Al[2][TB][KPAD];     // 2.5 KB
  __shared__ __align__(16) unsigned short Bh[2][NEXP][KPAD];   // 10 KB
  __shared__ __align__(16) unsigned short Bl[2][NEXP][KPAD];   // 10 KB
  __shared__ float lg[NEXP][TPAD];                             // 5 KB
  __shared__ float xn_lds[TB];
  __shared__ float snc[NEXP];

  const int tid  = threadIdx.x;
  const int t0   = blockIdx.x * TB;
  const int sr   = tid >> 3;          // A stage row (0..15), 8 threads/row
  const int sq   = (tid & 7) * 4;     // A stage col (f32x4)
  const int er   = tid >> 1;          // B stage row (0..63), 2 threads/row
  const int eq   = (tid & 1) * 16;    // B stage col (2x short8)
  const int lane = tid & 63;
  const int w    = tid >> 6;
  const int eh   = w * 32;            // wave's expert half
  const int fr   = lane & 15;
  const int fk   = (lane >> 4) * 8;

  if (tid < NEXP) snc[tid] = inv_nc[tid];

  const float*          xptr = x   + (size_t)(t0 + sr) * HDIM + sq;
  const unsigned short* bh_p = cbh + (size_t)er * HDIM + eq;
  const unsigned short* bl_p = cbl + (size_t)er * HDIM + eq;

  f32x4 xp;
  short8 bh0r, bh1r, bl0r, bl1r;
  float nacc = 0.f;

  auto stage = [&](int b) {
    unsigned h01, l01, h23, l23;
    cvt2(xp.x, xp.y, h01, l01);
    cvt2(xp.z, xp.w, h23, l23);
    *(uint2v*)&Ah[b][sr][sq] = (uint2v){h01, h23};
    *(uint2v*)&Al[b][sr][sq] = (uint2v){l01, l23};
    nacc += xp.x*xp.x + xp.y*xp.y + xp.z*xp.z + xp.w*xp.w;
    *(short8*)&Bh[b][er][eq]     = bh0r;
    *(short8*)&Bh[b][er][eq + 8] = bh1r;
    *(short8*)&Bl[b][er][eq]     = bl0r;
    *(short8*)&Bl[b][er][eq + 8] = bl1r;
  };
  auto ldreg = [&](int it) {
    const int o = it * KK;
    xp   = *(const f32x4*)(xptr + o);
    bh0r = *(const short8*)(bh_p + o);
    bh1r = *(const short8*)(bh_p + o + 8);
    bl0r = *(const short8*)(bl_p + o);
    bl1r = *(const short8*)(bl_p + o + 8);
  };

  ldreg(0);
  stage(0);
  ldreg(1);
  __syncthreads();

  f32x4 acc0 = (f32x4){0.f, 0.f, 0.f, 0.f};
  f32x4 acc1 = (f32x4){0.f, 0.f, 0.f, 0.f};

  for (int it = 0; it < 64; ++it) {
    const int cur = it & 1;
    short8 ah  = *(const short8*)&Ah[cur][fr][fk];
    short8 al  = *(const short8*)&Al[cur][fr][fk];
    short8 bh0 = *(const short8*)&Bh[cur][eh + fr][fk];
    short8 bl0 = *(const short8*)&Bl[cur][eh + fr][fk];
    short8 bh1 = *(const short8*)&Bh[cur][eh + 16 + fr][fk];
    short8 bl1 = *(const short8*)&Bl[cur][eh + 16 + fr][fk];
    if (it < 63) {
      stage(cur ^ 1);
      if (it < 62) ldreg(it + 2);
    }
    acc0 = __builtin_amdgcn_mfma_f32_16x16x32_bf16(ah, bh0, acc0, 0, 0, 0);
    acc0 = __builtin_amdgcn_mfma_f32_16x16x32_bf16(ah, bl0, acc0, 0, 0, 0);
    acc0 = __builtin_amdgcn_mfma_f32_16x16x32_bf16(al, bh0, acc0, 0, 0, 0);
    acc1 = __builtin_amdgcn_mfma_f32_16x16x32_bf16(ah, bh1, acc1, 0, 0, 0);
    acc1 = __builtin_amdgcn_mfma_f32_16x16x32_bf16(ah, bl1, acc1, 0, 0, 0);
    acc1 = __builtin_amdgcn_mfma_f32_16x16x32_bf16(al, bh1, acc1, 0, 0, 0);
    __syncthreads();
  }

  // token norms: 8 staging threads per row are contiguous lanes
  float s = nacc;
  s += __shfl_xor(s, 1, 64);
  s += __shfl_xor(s, 2, 64);
  s += __shfl_xor(s, 4, 64);
  if ((tid & 7) == 0) xn_lds[sr] = s;

  // logits -> LDS [e][t]; D frag: col(expert)=lane&15, row(token)=(lane>>4)*4+reg
  const int tb = (lane >> 4) * 4;
  *(f32x4*)&lg[eh + fr][tb]      = acc0;
  *(f32x4*)&lg[eh + 16 + fr][tb] = acc1;
  __syncthreads();

  if (tid < TB) {
    const int t  = tid;
    const int tg = t0 + t;
    const float inv_nx = 1.0f / fmaxf(sqrtf(xn_lds[t]), 1e-12f);
    float m1 = -1e30f, m2 = -1e30f, m3 = -1e30f;
    int i1 = 0, i2 = 0;
    #pragma unroll
    for (int e = 0; e < NEXP; ++e) {
      float l = lg[e][t] * snc[e] * inv_nx;
      if (l > m1)      { m3 = m2; m2 = m1; i2 = i1; m1 = l; i1 = e; }
      else if (l > m2) { m3 = m2; m2 = l; i2 = e; }
      else if (l > m3) { m3 = l; }
    }
    float Z = 0.f;
    #pragma unroll
    for (int e = 0; e < NEXP; ++e)
      Z += expf(lg[e][t] * snc[e] * inv_nx - m1);
    const float p1w = 1.0f / Z;
    const float p2w = expf(m2 - m1) / Z;
    const float s2  = p1w + p2w + 1e-9f;
    out[tg * 2 + 0] = (float)i1;
    out[tg * 2 + 1] = (float)i2;
    out[2 * NTOK + tg * 2 + 0] = p1w / s2;
    out[2 * NTOK + tg * 2 + 1] = p2w / s2;
    route[tg] = i1;
    // scatter (pre-refine; refine patches flipped tokens)
    const int p = atomicAdd(&cursor[i1], 1);
    atomicAdd(&cnt[i1], 1);
    if (p < MAXB) bucket[i1 * MAXB + p] = tg;
    posa[tg] = p;
    if ((m1 - m2) < TAU || (m2 - m3) < TAU) {
      int idx = atomicAdd(nflag, 1);
      flags[idx] = tg;
    }
  }
}

// Refine: block per flagged token; fp64 recompute + bucket fixup for flips.
__global__ __launch_bounds__(256)
void refine_np_kernel(const float* __restrict__ x, const float* __restrict__ bn,
                      float* __restrict__ out, int* __restrict__ route,
                      const int* __restrict__ nflag, const int* __restrict__ flags,
                      int* __restrict__ cursor, int* __restrict__ cnt,
                      int* __restrict__ bucket, int* __restrict__ posa) {
  __shared__ float a_lds[HDIM];
  __shared__ double redd[256];
  __shared__ float lf[NEXP];
  __shared__ float s_nx;
  const int tid  = threadIdx.x;
  const int lane = tid & 63;
  const int w    = tid >> 6;
  const int n = *nflag;
  for (int j = blockIdx.x; j < n; j += gridDim.x) {
    const int t = flags[j];
    const float* xr = x + (size_t)t * HDIM;
    double xacc = 0.0;
    #pragma unroll
    for (int i = 0; i < 8; ++i) {
      double v = (double)xr[tid + 256 * i];
      xacc += v * v;
    }
    double xn = block_reduce_sum_f64(xacc, redd);
    if (tid == 0) s_nx = (float)fmax(sqrt(xn), 1e-12);
    __syncthreads();
    const double nx = (double)s_nx;
    #pragma unroll
    for (int i = 0; i < 8; ++i) {
      int k = tid + 256 * i;
      a_lds[k] = (float)((double)xr[k] / nx);
    }
    __syncthreads();
    #pragma unroll 1
    for (int ei = 0; ei < 16; ++ei) {
      const int e = w * 16 + ei;
      const float* br = bn + (size_t)e * HDIM;
      double d = 0.0;
      #pragma unroll 8
      for (int i = 0; i < 32; ++i) {
        int k = lane + 64 * i;
        d += (double)a_lds[k] * (double)br[k];
      }
      #pragma unroll
      for (int o = 32; o > 0; o >>= 1) d += __shfl_down(d, o, 64);
      if (lane == 0) lf[e] = (float)d;
    }
    __syncthreads();
    if (tid == 0) {
      float m32 = lf[0];
      for (int ee = 1; ee < NEXP; ++ee) m32 = fmaxf(m32, lf[ee]);
      float ex[NEXP];
      for (int ee = 0; ee < NEXP; ++ee)
        ex[ee] = (float)exp((double)(lf[ee] - m32));
      float r[8];
      #pragma unroll
      for (int q = 0; q < 8; ++q) r[q] = ex[q];
      for (int i = 8; i < NEXP; i += 8)
        #pragma unroll
        for (int q = 0; q < 8; ++q) r[q] += ex[i + q];
      const float Z = ((r[0] + r[1]) + (r[2] + r[3])) + ((r[4] + r[5]) + (r[6] + r[7]));
      float p1 = -1.f, p2 = -1.f;
      int i1 = 0, i2 = 0;
      for (int ee = 0; ee < NEXP; ++ee) {
        float p = ex[ee] / Z;
        if (p > p1)      { p2 = p1; i2 = i1; p1 = p; i1 = ee; }
        else if (p > p2) { p2 = p; i2 = ee; }
      }
      const float s = (p1 + p2) + 1e-9f;
      out[t * 2 + 0] = (float)i1;
      out[t * 2 + 1] = (float)i2;
      out[2 * NTOK + t * 2 + 0] = p1 / s;
      out[2 * NTOK + t * 2 + 1] = p2 / s;
      const int old = route[t];
      if (i1 != old) {
        const int p_old = posa[t];
        if (p_old < MAXB) bucket[old * MAXB + p_old] = -1;   // punch hole
        atomicSub(&cnt[old], 1);
        const int p = atomicAdd(&cursor[i1], 1);
        atomicAdd(&cnt[i1], 1);
        if (p < MAXB) bucket[i1 * MAXB + p] = t;
        posa[t] = p;
        route[t] = i1;
      }
    }
    __syncthreads();
  }
}

// slow fallback refine (no bn dependency) for small-ws path
__global__ __launch_bounds__(64)
void refine_np_slow(const float* __restrict__ x, const float* __restrict__ c,
                    float* __restrict__ out, int* __restrict__ route,
                    const int* __restrict__ nflag, const int* __restrict__ flags) {
  __shared__ float lf[NEXP];
  const int e = threadIdx.x;
  const int n = *nflag;
  for (int j = blockIdx.x; j < n; j += gridDim.x) {
    const int t = flags[j];
    const float* xr = x + (size_t)t * HDIM;
    const float* cr = c + (size_t)e * HDIM;
    double xn = 0.0, cn = 0.0;
    for (int k = 0; k < HDIM; ++k) {
      double xv = (double)xr[k];
      double cv = (double)cr[k];
      xn += xv * xv;
      cn += cv * cv;
    }
    const float nx32 = (float)fmax(sqrt(xn), 1e-12);
    const float nc32 = (float)fmax(sqrt(cn), 1e-12);
    double d = 0.0;
    for (int k = 0; k < HDIM; ++k) {
      float a = (float)((double)xr[k] / (double)nx32);
      float b = (float)((double)cr[k] / (double)nc32);
      d += (double)a * (double)b;
    }
    lf[e] = (float)d;
    __syncthreads();
    if (e == 0) {
      float m32 = lf[0];
      for (int ee = 1; ee < NEXP; ++ee) m32 = fmaxf(m32, lf[ee]);
      float ex[NEXP];
      for (int ee = 0; ee < NEXP; ++ee)
        ex[ee] = (float)exp((double)(lf[ee] - m32));
      float r[8];
      #pragma unroll
      for (int q = 0; q < 8; ++q) r[q] = ex[q];
      for (int i = 8; i < NEXP; i += 8)
        #pragma unroll
        for (int q = 0; q < 8; ++q) r[q] += ex[i + q];
      const float Z = ((r[0] + r[1]) + (r[2] + r[3])) + ((r[4] + r[5]) + (r[6] + r[7]));
      float p1 = -1.f, p2 = -1.f;
      int i1 = 0, i2 = 0;
      for (int ee = 0; ee < NEXP; ++ee) {
        float p = ex[ee] / Z;
        if (p > p1)      { p2 = p1; i2 = i1; p1 = p; i1 = ee; }
        else if (p > p2) { p2 = p; i2 = ee; }
      }
      const float s = (p1 + p2) + 1e-9f;
      out[t * 2 + 0] = (float)i1;
      out[t * 2 + 1] = (float)i2;
      out[2 * NTOK + t * 2 + 0] = p1 / s;
      out[2 * NTOK + t * 2 + 1] = p2 / s;
      route[t] = i1;
    }
    __syncthreads();
  }
}

// Per-expert partial sums, 4-way token split: block = (expert, hchunk, tsplit).
// grid = 64*8*4 = 2048 blocks (8/CU). Skips -1 sentinel holes from refine fixup.
__global__ __launch_bounds__(256)
void segsum_part(const float* __restrict__ x, const int* __restrict__ cursor,
                 const int* __restrict__ bucket, float* __restrict__ psum) {
  __shared__ f32x4 part[4][64];
  const int e   = blockIdx.x >> 5;
  const int hc  = (blockIdx.x >> 2) & 7;
  const int ts  = blockIdx.x & 3;
  const int hb  = hc * 256;
  const int tid = threadIdx.x;
  const int rg  = tid >> 6;
  const int cc  = tid & 63;
  int n = cursor[e];
  if (n > MAXB) n = MAXB;
  const int nq = (n + 3) >> 2;
  const int lo = ts * nq;
  const int hi = min(lo + nq, n);
  const int* bk = bucket + e * MAXB;
  f32x4 a = (f32x4){0.f, 0.f, 0.f, 0.f};
  #pragma unroll 4
  for (int i = lo + rg; i < hi; i += 4) {
    const int r = bk[i];
    if (r >= 0) a += *(const f32x4*)(x + (size_t)r * HDIM + hb + cc * 4);
  }
  part[rg][cc] = a;
  __syncthreads();
  if (tid < 64) {
    f32x4 s = part[0][tid] + part[1][tid] + part[2][tid] + part[3][tid];
    *(f32x4*)&psum[(size_t)(ts * NEXP + e) * HDIM + hb + tid * 4] = s;
  }
}

__global__ __launch_bounds__(256)
void finalize4_kernel(const float* __restrict__ c, const float* __restrict__ psum,
                      const int* __restrict__ counts, float* __restrict__ out) {
  __shared__ float red[4];
  const int e = blockIdx.x;
  const int tid = threadIdx.x;
  const float cnt = (float)counts[e];
  const float minv = 1.0f / (cnt + 1e-6f);
  float u[8], cv[8];
  float ss = 0.f;
  #pragma unroll
  for (int j = 0; j < 8; ++j) {
    int h = tid + j * 256;
    cv[j] = c[e * HDIM + h];
    float sm = psum[(size_t)(0 * NEXP + e) * HDIM + h]
             + psum[(size_t)(1 * NEXP + e) * HDIM + h]
             + psum[(size_t)(2 * NEXP + e) * HDIM + h]
             + psum[(size_t)(3 * NEXP + e) * HDIM + h];
    float mean = sm * minv;
    u[j] = 0.9f * cv[j] + 0.1f * mean;
    ss += u[j] * u[j];
  }
  float tot = block_reduce_sum(ss, red);
  float sc = 1.0f / fmaxf(sqrtf(tot), 1e-12f);
  const bool nz = cnt > 0.f;
  #pragma unroll
  for (int j = 0; j < 8; ++j) {
    int h = tid + j * 256;
    out[4 * NTOK + e * HDIM + h] = nz ? u[j] * sc : cv[j];
  }
}

__global__ __launch_bounds__(256)
void finalize_kernel(const float* __restrict__ c, const float* __restrict__ sums,
                     const int* __restrict__ counts, float* __restrict__ out) {
  __shared__ float red[4];
  const int e = blockIdx.x;
  const int tid = threadIdx.x;
  const float cnt = (float)counts[e];
  const float minv = 1.0f / (cnt + 1e-6f);
  float u[8], cv[8];
  float ss = 0.f;
  #pragma unroll
  for (int j = 0; j < 8; ++j) {
    int h = tid + j * 256;
    cv[j] = c[e * HDIM + h];
    float mean = sums[e * HDIM + h] * minv;
    u[j] = 0.9f * cv[j] + 0.1f * mean;
    ss += u[j] * u[j];
  }
  float tot = block_reduce_sum(ss, red);
  float sc = 1.0f / fmaxf(sqrtf(tot), 1e-12f);
  const bool nz = cnt > 0.f;
  #pragma unroll
  for (int j = 0; j < 8; ++j) {
    int h = tid + j * 256;
    out[4 * NTOK + e * HDIM + h] = nz ? u[j] * sc : cv[j];
  }
}

// ---- fallback path kernels (small ws): R5 router + old segsum ----
__global__ __launch_bounds__(256)
void router_kernel(const float* __restrict__ x, const float* __restrict__ c,
                   const float* __restrict__ inv_nc, float* __restrict__ out,
                   int* __restrict__ route, int* __restrict__ nflag,
                   int* __restrict__ flags) {
  __shared__ __align__(16) float xs[64][36];
  __shared__ float lgs[64][67];
  const int tid  = threadIdx.x;
  const int lane = tid & 63;
  const int w    = tid >> 6;
  const int t0   = blockIdx.x * 64;
  const int e0   = __builtin_amdgcn_readfirstlane(w * 16);
  const float* cb = c + (size_t)e0 * HDIM;
  const int st = tid >> 3;
  const int sk = (tid & 7) * 4;
  float acc[16];
  #pragma unroll
  for (int e = 0; e < 16; ++e) acc[e] = 0.f;
  float nacc = 0.f;
  float4 p0 = *(const float4*)&x[(size_t)(t0 + st)      * HDIM + sk];
  float4 p1 = *(const float4*)&x[(size_t)(t0 + st + 32) * HDIM + sk];
  for (int k0 = 0; k0 < HDIM; k0 += 32) {
    __syncthreads();
    *(float4*)&xs[st][sk]      = p0;
    *(float4*)&xs[st + 32][sk] = p1;
    __syncthreads();
    const int kn = k0 + 32;
    if (kn < HDIM) {
      p0 = *(const float4*)&x[(size_t)(t0 + st)      * HDIM + kn + sk];
      p1 = *(const float4*)&x[(size_t)(t0 + st + 32) * HDIM + kn + sk];
    }
    float a[32];
    #pragma unroll
    for (int j = 0; j < 32; j += 4) {
      float4 v = *(const float4*)&xs[lane][j];
      a[j] = v.x; a[j+1] = v.y; a[j+2] = v.z; a[j+3] = v.w;
    }
    if (w == 0) {
      #pragma unroll
      for (int j = 0; j < 32; ++j) nacc += a[j] * a[j];
    }
    #pragma unroll
    for (int e = 0; e < 16; ++e) {
      const float* br = cb + (size_t)e * HDIM + k0;
      #pragma unroll
      for (int j = 0; j < 32; j += 4) {
        float4 bv = *(const float4*)&br[j];
        acc[e] += a[j]*bv.x + a[j+1]*bv.y + a[j+2]*bv.z + a[j+3]*bv.w;
      }
    }
  }
  #pragma unroll
  for (int e = 0; e < 16; ++e) lgs[lane][e0 + e] = acc[e] * inv_nc[e0 + e];
  __syncthreads();
  if (w == 0) {
    const float inv_nx = 1.0f / fmaxf(sqrtf(nacc), 1e-12f);
    float m1 = -1e30f, m2 = -1e30f, m3 = -1e30f;
    int i1 = 0, i2 = 0;
    for (int e = 0; e < NEXP; ++e) {
      float l = lgs[lane][e] * inv_nx;
      if (l > m1)      { m3 = m2; m2 = m1; i2 = i1; m1 = l; i1 = e; }
      else if (l > m2) { m3 = m2; m2 = l; i2 = e; }
      else if (l > m3) { m3 = l; }
    }
    float Z = 0.f;
    for (int e = 0; e < NEXP; ++e) Z += expf(lgs[lane][e] * inv_nx - m1);
    const float p1w = 1.0f / Z;
    const float p2w = expf(m2 - m1) / Z;
    const float s   = p1w + p2w + 1e-9f;
    const int tg = t0 + lane;
    out[tg * 2 + 0] = (float)i1;
    out[tg * 2 + 1] = (float)i2;
    out[2 * NTOK + tg * 2 + 0] = p1w / s;
    out[2 * NTOK + tg * 2 + 1] = p2w / s;
    route[tg] = i1;
    if ((m1 - m2) < TAU || (m2 - m3) < TAU) {
      int idx = atomicAdd(nflag, 1);
      flags[idx] = tg;
    }
  }
}

__global__ __launch_bounds__(512)
void segsum_kernel(const float* __restrict__ x, const int* __restrict__ route,
                   float* __restrict__ sums, int* __restrict__ counts) {
  __shared__ float ls[NEXP * 256];
  __shared__ int lcnt[NEXP];
  const int tid  = threadIdx.x;
  const int lane = tid & 63;
  const int w    = tid >> 6;
  const int hc   = blockIdx.x & 7;
  const int tg   = blockIdx.x >> 3;
  const int hb   = hc * 256;
  #pragma unroll
  for (int i = 0; i < 32; ++i) ls[tid + i * 512] = 0.f;
  if (tid < NEXP) lcnt[tid] = 0;
  __syncthreads();
  const int tbase = tg * 512 + w * 64;
  #pragma unroll 4
  for (int i = 0; i < 64; ++i) {
    const int t = tbase + i;
    const int e = route[t];
    const float* xr = x + (size_t)t * HDIM + hb + lane;
    #pragma unroll
    for (int j = 0; j < 4; ++j)
      atomicAdd(&ls[e * 256 + lane + 64 * j], xr[64 * j]);
    if (hc == 0 && lane == 0) atomicAdd(&lcnt[e], 1);
  }
  __syncthreads();
  #pragma unroll
  for (int i = tid; i < NEXP * 256; i += 512) {
    const int e = i >> 8, h = i & 255;
    atomicAdd(&sums[e * HDIM + hb + h], ls[i]);
  }
  if (hc == 0 && tid < NEXP && lcnt[tid] > 0) atomicAdd(&counts[tid], lcnt[tid]);
}

extern "C" void kernel_launch(void* const* d_in, const int* in_sizes, int n_in,
                              void* d_out, int out_size, void* d_ws, size_t ws_size,
                              hipStream_t stream) {
  const float* x = (const float*)d_in[0];
  const float* c = (const float*)d_in[1];
  float* out = (float*)d_out;
  float* ws = (float*)d_ws;

  float* inv_nc = ws;
  int*   cursor = (int*)(ws + 64);
  int*   nflag  = (int*)(ws + 128);
  int*   route  = (int*)(ws + 192);
  int*   flags  = (int*)(ws + 16576);
  float* sums   = ws + 32960;           // fallback path only
  float* bn     = ws + 164032;
  unsigned short* cbh = (unsigned short*)(ws + 295104);
  unsigned short* cbl = (unsigned short*)(ws + 360640);
  int*   bucket = (int*)(ws + 426176);
  float* psum   = ws + 557248;
  int*   posa   = (int*)(ws + 1081536);
  int*   cnt    = (int*)(ws + 1097920);

  const size_t NEED = 1097984ull * 4ull;
  if (ws_size >= NEED) {
    cprep_kernel<<<NEXP, 256, 0, stream>>>(c, inv_nc, bn, cbh, cbl, cursor, cnt);
    fused_kernel<<<NTOK / TB, 128, 0, stream>>>(x, cbh, cbl, inv_nc, out, route,
                                                nflag, flags, cursor, cnt, bucket, posa);
    refine_np_kernel<<<512, 256, 0, stream>>>(x, bn, out, route, nflag, flags,
                                              cursor, cnt, bucket, posa);
    segsum_part<<<2048, 256, 0, stream>>>(x, cursor, bucket, psum);
    finalize4_kernel<<<NEXP, 256, 0, stream>>>(c, psum, cnt, out);
  } else {
    zero_kernel<<<1, 256, 0, stream>>>(ws + 64, 128);
    zero_kernel<<<512, 256, 0, stream>>>(sums, 131072);
    cnorm_kernel<<<NEXP, 256, 0, stream>>>(c, inv_nc);
    router_kernel<<<NTOK / 64, 256, 0, stream>>>(x, c, inv_nc, out, route, nflag, flags);
    refine_np_slow<<<1024, 64, 0, stream>>>(x, c, out, route, nflag, flags);
    segsum_kernel<<<256, 512, 0, stream>>>(x, route, sums, cursor);
    finalize_kernel<<<NEXP, 256, 0, stream>>>(c, sums, cursor, out);
  }
}